// Round 7
// baseline (205.445 us; speedup 1.0000x reference)
//
#include <hip/hip_runtime.h>

#define BINS 128
#define FEAT 64
#define SEG (BINS * FEAT)     // 8192 counters per batch histogram
#define B_DIM 32
#define S_DIM 16384
#define CHUNKS 16             // S-chunks per batch -> 512 blocks (2 per CU)
#define THREADS 512           // 8 waves
#define ROWS_PER_BLOCK (S_DIM / CHUNKS)                // 1024
#define ROWS_PER_WAVE  (ROWS_PER_BLOCK / (THREADS/64)) // 128
// One row = 64 floats = 16 float4. One wave-load (64 lanes x float4) = 4 rows.
// Wave iterates k = 0..31 over its 128-row slab: flat float4 idx = k*64 + lane.
// Since 64 % 16 == 0, feature group = (lane & 15) is loop-invariant.

__global__ __launch_bounds__(THREADS, 4)   // 2 blocks/CU (16 waves), LDS 2x32K
void hist_fused_kernel(const float4* __restrict__ x4,
                       const float* __restrict__ w,
                       float* __restrict__ out) {
    __shared__ unsigned hist[SEG];
    for (int i = threadIdx.x; i < SEG; i += THREADS) hist[i] = 0u;
    __syncthreads();

    const int c    = blockIdx.x;
    const int b    = blockIdx.y;
    const int lane = threadIdx.x & 63;
    const int wave = threadIdx.x >> 6;               // 0..7
    const int f0   = (lane & 15) << 2;               // loop-invariant feature base

    // base in float4 units: 16 float4 per row
    const size_t base = ((size_t)b * S_DIM
                         + (size_t)c * ROWS_PER_BLOCK
                         + (size_t)wave * ROWS_PER_WAVE) * 16 + lane;

    #pragma unroll 8
    for (int k = 0; k < 32; ++k) {                   // 4 rows per k, 128 rows total
        float4 v = x4[base + (size_t)k * 64];        // global_load_dwordx4, 1KiB/wave
        int b0 = (int)(v.x * 128.0f); b0 = b0 < 0 ? 0 : (b0 > 127 ? 127 : b0);
        int b1 = (int)(v.y * 128.0f); b1 = b1 < 0 ? 0 : (b1 > 127 ? 127 : b1);
        int b2 = (int)(v.z * 128.0f); b2 = b2 < 0 ? 0 : (b2 > 127 ? 127 : b2);
        int b3 = (int)(v.w * 128.0f); b3 = b3 < 0 ? 0 : (b3 > 127 ? 127 : b3);
        // 4 lanes share each bank group (4-way alias, ~1.58x on LDS pipe),
        // hidden under the global-load budget.
        atomicAdd(&hist[(b0 << 6) + f0 + 0], 1u);    // ds_add_u32
        atomicAdd(&hist[(b1 << 6) + f0 + 1], 1u);
        atomicAdd(&hist[(b2 << 6) + f0 + 2], 1u);
        atomicAdd(&hist[(b3 << 6) + f0 + 3], 1u);
    }
    __syncthreads();

    // Merge with weights fused (identical to R4, proven): 16 atomics/thread.
    float* gout = out + (size_t)b * SEG;             // out[b][bin][f] == hist layout
    for (int i = threadIdx.x; i < SEG; i += THREADS) {
        unsigned cnt = hist[i];
        if (cnt) atomicAdd(&gout[i], (float)cnt * w[i]);  // global_atomic_add_f32
    }
}

extern "C" void kernel_launch(void* const* d_in, const int* in_sizes, int n_in,
                              void* d_out, int out_size, void* d_ws, size_t ws_size,
                              hipStream_t stream) {
    const float4* x4 = (const float4*)d_in[0];
    const float* w = (const float*)d_in[1];
    float* out = (float*)d_out;

    // d_out is poisoned 0xAA before every call -> zero it (1 MiB, ~0.3 us).
    hipMemsetAsync(d_out, 0, (size_t)out_size * sizeof(float), stream);

    dim3 grid(CHUNKS, B_DIM);
    hist_fused_kernel<<<grid, THREADS, 0, stream>>>(x4, w, out);
}